// Round 6
// baseline (3275.304 us; speedup 1.0000x reference)
//
#include <hip/hip_runtime.h>
#include <hip/hip_bf16.h>
#include <math.h>

// Problem constants (fixed by setup_inputs): B=64, L=512, D_IN=256, H=256, A=128, DEPTH=4
#define BB 64
#define LL 512
#define HH 256
#define H3 768
#define AA 128
#define NDEPTH 4
#define NROWS (LL*BB)   // 32768

// dedicated exchange region:
//   u64 exch[64 chains][2 parity][3 slices][256]  = 786,432 B
#define EXCH_U64_PER_CHAIN (2 * 3 * 256)

typedef float vf32x32 __attribute__((ext_vector_type(32)));

// padded h storage: k-chunk c (32 floats) lives at [36*c, 36*c+32)
// -> GEMV float4 reads at 36*kg+4i are 16B-aligned and spread banks
//    4*(kg+i)%32: conflict-free across the 8 kg lanes of a wave.
#define HIDX(c) (36 * ((c) >> 5) + ((c) & 31))
#define HPAD 284

// compile-time U-register select (f must fold to a constant in unrolled loops)
#define UVAL(f) ((f) < 32 ? u0v[(f)] : (f) < 64 ? u1v[(f)-32] \
                : (f) < 96 ? u2v[(f)-64] : u3v[(f)-96])

// ---------------------------------------------------------------------------
// Mask conversion: detect byte-bool vs int32/float32 layout on device.
__global__ void maskcvt_kernel(const unsigned char* __restrict__ raw,
                               int* __restrict__ m)
{
    int i = blockIdx.x * blockDim.x + threadIdx.x;   // 32768 threads
    bool bytemode = (raw[1] == 1);
    int v;
    if (bytemode) v = raw[i] ? 1 : 0;
    else          v = (((const int*)raw)[i] != 0) ? 1 : 0;
    m[i] = v;
}

// ---------------------------------------------------------------------------
// Per-chain compaction index.
__global__ __launch_bounds__(512) void mkidx_kernel(
    const int* __restrict__ m,
    int* __restrict__ rowidx,
    int* __restrict__ nact)
{
    const int b    = blockIdx.x;
    const int tid  = threadIdx.x;   // = l
    const int lane = tid & 63;
    const int w    = tid >> 6;      // 8 waves
    __shared__ int wcnt[8];
    int pred = m[b * LL + tid];
    unsigned long long bal = __ballot(pred != 0);
    int below = __popcll(bal & ((1ull << lane) - 1ull));
    if (lane == 63) wcnt[w] = __popcll(bal);
    __syncthreads();
    int woff = 0;
#pragma unroll
    for (int i = 0; i < 8; ++i) woff += (i < w) ? wcnt[i] : 0;
    if (pred) rowidx[b * LL + woff + below] = tid;
    if (tid == 511) nact[b] = woff + wcnt[7];
}

// ---------------------------------------------------------------------------
// Tiled fp32 GEMM: C[M,N] = A[M,256] @ B[256,N]  (K fixed at 256)
// LDS stride 132 (write-side 2-way, free). Round-6: thread's 8 cols are
// {tx*4..+3} u {64+tx*4..+3} (bases 4*tx mod 32, period 8 -> 2-way free)
// instead of tx*8 (period 4 -> 4-way read conflict on Bs inner loop).
template<int MODE, int EPI>
__global__ __launch_bounds__(256) void gemm_kernel(
    const float* __restrict__ A, const float* __restrict__ Bm,
    const float* __restrict__ bias,
    float* __restrict__ C, int M, int N,
    const int* __restrict__ ridx, const int* __restrict__ nact)
{
    __shared__ float As[16][132];
    __shared__ float Bs[16][132];
    const int tid = threadIdx.x;
    const int tx = tid & 15, ty = tid >> 4;
    const int row0 = blockIdx.y * 128, col0 = blockIdx.x * 128;

    int arow0 = 0, arow1 = 0;
    if (MODE == 3) {
        const int bb = row0 >> 9;
        const int na = nact[bb];
        if ((row0 & 511) >= na) return;
        const int r0 = row0 + (tid >> 2);
        const int r1 = r0 + 64;
        const int l0 = ((r0 & 511) < na) ? ridx[r0] : 0;
        const int l1 = ((r1 & 511) < na) ? ridx[r1] : 0;
        arow0 = l0 * 64 + bb;
        arow1 = l1 * 64 + bb;
    }

    float acc[8][8];
#pragma unroll
    for (int i = 0; i < 8; ++i)
#pragma unroll
        for (int j = 0; j < 8; ++j) acc[i][j] = 0.f;

    for (int kk = 0; kk < 256; kk += 16) {
#pragma unroll
        for (int i = 0; i < 2; ++i) {
            int aid = i * 256 + tid;
            int r   = aid >> 2;
            int k4  = (aid & 3) << 2;
            int rr  = row0 + r;
            float4 v;
            if (MODE == 1) {
                v = *(const float4*)(A + (rr & 63) * 131072 + (rr >> 6) * 256 + kk + k4);
            } else {
                int ar = i ? arow1 : arow0;
                v = *(const float4*)(A + ar * 256 + kk + k4);
            }
            As[k4 + 0][r] = v.x; As[k4 + 1][r] = v.y;
            As[k4 + 2][r] = v.z; As[k4 + 3][r] = v.w;

            int bid = i * 256 + tid;
            int bk  = bid >> 5;
            int c4  = (bid & 31) << 2;
            float4 w = *(const float4*)(Bm + (kk + bk) * N + col0 + c4);
            *(float4*)&Bs[bk][c4] = w;
        }
        __syncthreads();
#pragma unroll
        for (int k = 0; k < 16; ++k) {
            float a[8], bb2[8];
            *(float4*)&a[0]   = *(const float4*)&As[k][ty * 8];
            *(float4*)&a[4]   = *(const float4*)&As[k][ty * 8 + 4];
            *(float4*)&bb2[0] = *(const float4*)&Bs[k][tx * 4];
            *(float4*)&bb2[4] = *(const float4*)&Bs[k][64 + tx * 4];
#pragma unroll
            for (int i = 0; i < 8; ++i)
#pragma unroll
                for (int j = 0; j < 8; ++j)
                    acc[i][j] += a[i] * bb2[j];
        }
        __syncthreads();
    }

#pragma unroll
    for (int i = 0; i < 8; ++i) {
        int row   = row0 + ty * 8 + i;
        int colb0 = col0 + tx * 4;
        int colb1 = col0 + 64 + tx * 4;
        float v0[4], v1[4];
#pragma unroll
        for (int j = 0; j < 4; ++j) {
            float a0 = acc[i][j], a1 = acc[i][4 + j];
            if (EPI == 1) { a0 += bias[colb0 + j]; a1 += bias[colb1 + j]; }
            v0[j] = a0; v1[j] = a1;
        }
        *(float4*)&C[row * N + colb0] = *(float4*)&v0[0];
        *(float4*)&C[row * N + colb1] = *(float4*)&v1[0];
    }
}

// ---------------------------------------------------------------------------
// Row LayerNorm over 768 cols, in place, fused with gamma/beta and gate bias.
__global__ __launch_bounds__(256) void lnrows_kernel(
    float* __restrict__ XP, const float* __restrict__ g0,
    const float* __restrict__ b0, const float* __restrict__ gb,
    const int* __restrict__ nact)
{
    const int row = blockIdx.x;
    if ((row & 511) >= nact[row >> 9]) return;
    const int tid = threadIdx.x;
    float* p = XP + (long)row * H3;
    float v0 = p[tid], v1 = p[tid + 256], v2 = p[tid + 512];
    float s = v0 + v1 + v2;
    float q = v0 * v0 + v1 * v1 + v2 * v2;
#pragma unroll
    for (int off = 32; off >= 1; off >>= 1) {
        s += __shfl_xor(s, off);
        q += __shfl_xor(q, off);
    }
    __shared__ float rs4[4], rq4[4];
    if ((tid & 63) == 0) { rs4[tid >> 6] = s; rq4[tid >> 6] = q; }
    __syncthreads();
    float S = rs4[0] + rs4[1] + rs4[2] + rs4[3];
    float Q = rq4[0] + rq4[1] + rq4[2] + rq4[3];
    float mu  = S * (1.f / 768.f);
    float var = Q * (1.f / 768.f) - mu * mu;
    float r   = rsqrtf(var + 1e-5f);
    p[tid]       = g0[tid]       * (v0 - mu) * r + b0[tid]       + gb[tid];
    p[tid + 256] = g0[tid + 256] * (v1 - mu) * r + b0[tid + 256] + gb[tid + 256];
    p[tid + 512] = g0[tid + 512] * (v2 - mu) * r + b0[tid + 512] + gb[tid + 512];
}

// ---------------------------------------------------------------------------
// Blocks [0,192): GRU scan (3 wgs/chain). Blocks [192,448): XA GEMM, retire.
// Round-6 scan step restructure (exchange itself unchanged -- agent-scope
// relaxed publish/poll is the proven floor, rounds 5-15):
//   OLD chain: GEMV(kg=tid>>5) -> 8 ds_write part -> B1 -> 16 ds_read +
//              15 dependent adds -> publish -> poll -> ...
//   NEW: kg = tid&7 owns k-chunk [32kg,+32), 4 consecutive cols per thread
//        (cp = tid>>3). k-reduce = 3 in-wave shfl_xor (lane bits 0-2) --
//        no part[] (16KB LDS freed), no cross-wave LDS hop, and the publish
//        issues BEFORE B1, so peer visibility (~LLC) overlaps the local
//        vrow write + barrier + stats prep instead of serializing after.
//   h state padded (HIDX): float4 GEMV reads conflict-free across kg lanes.
__global__ __launch_bounds__(512, 2) void scan3_kernel(
    const float* __restrict__ XP,
    const float* __restrict__ U,
    const float* __restrict__ g1, const float* __restrict__ b1,
    const int* __restrict__ mask,
    float* __restrict__ Y,
    unsigned long long* __restrict__ exch,
    int seq0,
    const float* __restrict__ Xc,
    const float* __restrict__ Wa1,
    const float* __restrict__ ba1,
    float* __restrict__ XA)
{
    __shared__ float h_pad[HPAD];
    __shared__ float vrow[256];
    __shared__ float xp_lds[768];
    __shared__ float g1s[768], b1s[768];
    __shared__ int   mk[512];
    __shared__ float reds[4], redq[4];
    __shared__ float As[16][132];
    __shared__ float Bs[16][132];

    const int tid = threadIdx.x;

    if (blockIdx.x >= 192) {
        // ---- XA tile: 128 rows x 128 cols, K=256, 512 threads ----
        const int t    = blockIdx.x - 192;
        const int row0 = t * 128;
        const int tx   = tid & 15;
        const int ty4  = tid >> 4;
        float xacc[4][8];
#pragma unroll
        for (int i = 0; i < 4; ++i)
#pragma unroll
            for (int j = 0; j < 8; ++j) xacc[i][j] = 0.f;

        for (int kk = 0; kk < 256; kk += 16) {
            {
                int r  = tid >> 2;
                int k4 = (tid & 3) << 2;
                float4 v = *(const float4*)(Xc + (row0 + r) * 256 + kk + k4);
                As[k4 + 0][r] = v.x; As[k4 + 1][r] = v.y;
                As[k4 + 2][r] = v.z; As[k4 + 3][r] = v.w;
            }
            {
                int bk = tid >> 5;
                int c4 = (tid & 31) << 2;
                float4 w = *(const float4*)(Wa1 + (kk + bk) * AA + c4);
                *(float4*)&Bs[bk][c4] = w;
            }
            __syncthreads();
#pragma unroll
            for (int k = 0; k < 16; ++k) {
                float a[4], bb2[8];
                *(float4*)&a[0]   = *(const float4*)&As[k][ty4 * 4];
                *(float4*)&bb2[0] = *(const float4*)&Bs[k][tx * 4];
                *(float4*)&bb2[4] = *(const float4*)&Bs[k][64 + tx * 4];
#pragma unroll
                for (int i = 0; i < 4; ++i)
#pragma unroll
                    for (int j = 0; j < 8; ++j)
                        xacc[i][j] += a[i] * bb2[j];
            }
            __syncthreads();
        }
#pragma unroll
        for (int i = 0; i < 4; ++i) {
            int row = row0 + ty4 * 4 + i;
            float v0[4], v1[4];
#pragma unroll
            for (int j = 0; j < 4; ++j) {
                v0[j] = xacc[i][j]     + ba1[tx * 4 + j];
                v1[j] = xacc[i][4 + j] + ba1[64 + tx * 4 + j];
            }
            *(float4*)&XA[row * AA + tx * 4]      = *(float4*)&v0[0];
            *(float4*)&XA[row * AA + 64 + tx * 4] = *(float4*)&v1[0];
        }
        return;
    }

    // ---- scan path ----
    const int i0   = blockIdx.x;
    const int xcd  = i0 & 7;
    const int slot = i0 >> 3;              // 0..23
    const int b    = xcd + 8 * (slot / 3); // chain 0..63
    const int s    = slot % 3;             // slice 0..2
    const int kg   = tid & 7;              // k-chunk [32kg, +32)
    const int cp   = tid >> 3;             // col quad: s*256 + 4cp + 0..3
    const int q1   = (s + 1 >= 3) ? s - 2 : s + 1;
    const int q2   = (s + 2 >= 3) ? s - 1 : s + 2;

    // U slice -> registers via volatile loads (pinned against remat/sinking).
    // u[f], f = i*16 + e*4 + cj  <->  U[32kg + 4i + e][s*256 + 4cp + cj]
    vf32x32 u0v, u1v, u2v, u3v;
    {
        const volatile float* Uv = U;
        const int colbase = s * 256 + 4 * cp;
#pragma unroll
        for (int i = 0; i < 8; ++i) {
#pragma unroll
            for (int t = 0; t < 16; ++t) {
                const int e = t >> 2, cj = t & 3;
                const int f = i * 16 + t;
                float val = Uv[(32 * kg + 4 * i + e) * H3 + colbase + cj];
                if      (f < 32) u0v[f]      = val;
                else if (f < 64) u1v[f - 32] = val;
                else if (f < 96) u2v[f - 64] = val;
                else             u3v[f - 96] = val;
            }
        }
    }
    for (int i = tid; i < HPAD; i += 512) h_pad[i] = 0.f;
    for (int i = tid; i < 768; i += 512) { g1s[i] = g1[i]; b1s[i] = b1[i]; }
    mk[tid] = mask[b * LL + tid];
    __syncthreads();

    unsigned long long* exb = exch + b * EXCH_U64_PER_CHAIN;
    int seq = seq0;

    for (int l = 0; l < LL; ++l) {
        if (!mk[l]) {
            // masked step: h unchanged, Y row = h (slice 0 writes)
            if (s == 0 && tid < 64) {
                float4 hv = *(const float4*)&h_pad[HIDX(tid * 4)];
                *(float4*)&Y[((long)l * BB + b) * HH + tid * 4] = hv;
            }
            continue;
        }
        seq++;
        const int par = seq & 1;
        const int cs  = seq - seq0 - 1;        // compacted XP row index

        // prefetch compacted xp row (in flight during GEMV)
        float4 xr4;
        if (tid < 192) xr4 = *(const float4*)(XP + ((long)(b * LL + cs)) * H3 + tid * 4);

        // GEMV: thread sums its k-chunk for its 4 cols
        float a0 = 0.f, a1 = 0.f, a2 = 0.f, a3 = 0.f;
#pragma unroll
        for (int i = 0; i < 8; ++i) {
            const float4 hv = *(const float4*)&h_pad[36 * kg + 4 * i];
#pragma unroll
            for (int e = 0; e < 4; ++e) {
                const float hh = (e == 0) ? hv.x : (e == 1) ? hv.y
                               : (e == 2) ? hv.z : hv.w;
                const int fb = i * 16 + e * 4;
                a0 += UVAL(fb + 0) * hh;
                a1 += UVAL(fb + 1) * hh;
                a2 += UVAL(fb + 2) * hh;
                a3 += UVAL(fb + 3) * hh;
            }
        }
        // in-wave k-reduce over the 8 kg lanes (lane bits 0..2)
#pragma unroll
        for (int off = 1; off < 8; off <<= 1) {
            a0 += __shfl_xor(a0, off);
            a1 += __shfl_xor(a1, off);
            a2 += __shfl_xor(a2, off);
            a3 += __shfl_xor(a3, off);
        }

        // publish EARLY (before B1): peer visibility overlaps local work.
        if (kg < 2) {
            const int c0 = 4 * cp + 2 * kg;
            const float pv0 = (kg == 0) ? a0 : a2;
            const float pv1 = (kg == 0) ? a1 : a3;
            unsigned long long pk0 =
                ((unsigned long long)(unsigned)seq << 32) |
                (unsigned long long)__float_as_uint(pv0);
            unsigned long long pk1 =
                ((unsigned long long)(unsigned)seq << 32) |
                (unsigned long long)__float_as_uint(pv1);
            __hip_atomic_store(&exb[(par * 3 + s) * 256 + c0], pk0,
                               __ATOMIC_RELAXED, __HIP_MEMORY_SCOPE_AGENT);
            __hip_atomic_store(&exb[(par * 3 + s) * 256 + c0 + 1], pk1,
                               __ATOMIC_RELAXED, __HIP_MEMORY_SCOPE_AGENT);
        } else if (kg == 2) {
            vrow[4 * cp]     = a0;
            vrow[4 * cp + 1] = a1;
        } else if (kg == 3) {
            vrow[4 * cp + 2] = a2;
            vrow[4 * cp + 3] = a3;
        }
        __syncthreads();                               // B1: vrow complete

        if (tid < 192) *(float4*)&xp_lds[tid * 4] = xr4;

        float pre = 0.f, v0 = 0.f, v1 = 0.f, v2 = 0.f;
        if (tid < 256) {
            pre = vrow[tid];

            // fused dual-poll on the two peer slices (agent scope)
            unsigned long long x1 = 0, x2 = 0;
            bool d1 = false, d2 = false;
            int spins = 0;
            do {
                unsigned long long t1 =
                    __hip_atomic_load(&exb[(par * 3 + q1) * 256 + tid],
                                      __ATOMIC_RELAXED, __HIP_MEMORY_SCOPE_AGENT);
                unsigned long long t2 =
                    __hip_atomic_load(&exb[(par * 3 + q2) * 256 + tid],
                                      __ATOMIC_RELAXED, __HIP_MEMORY_SCOPE_AGENT);
                if (!d1 && (int)(t1 >> 32) == seq) { x1 = t1; d1 = true; }
                if (!d2 && (int)(t2 >> 32) == seq) { x2 = t2; d2 = true; }
                if (++spins > 8) __builtin_amdgcn_s_sleep(1);
            } while (!(d1 && d2));
            float w1 = __uint_as_float((unsigned)x1);
            float w2 = __uint_as_float((unsigned)x2);
            v0 = (s == 0) ? pre : ((q1 == 0) ? w1 : w2);
            v1 = (s == 1) ? pre : ((q1 == 1) ? w1 : w2);
            v2 = (s == 2) ? pre : ((q1 == 2) ? w1 : w2);

            float st = v0 + v1 + v2;
            float qt = v0 * v0 + v1 * v1 + v2 * v2;
#pragma unroll
            for (int off = 32; off >= 1; off >>= 1) {
                st += __shfl_xor(st, off);
                qt += __shfl_xor(qt, off);
            }
            if ((tid & 63) == 0) { reds[tid >> 6] = st; redq[tid >> 6] = qt; }
        }
        __syncthreads();                               // B2: stats partials

        if (tid < 256) {
            float S = reds[0] + reds[1] + reds[2] + reds[3];
            float Q = redq[0] + redq[1] + redq[2] + redq[3];
            float mu = S * (1.f / 768.f);
            float rs = rsqrtf(Q * (1.f / 768.f) - mu * mu + 1e-5f);
            float hp_r = g1s[tid]       * (v0 - mu) * rs + b1s[tid];
            float hp_z = g1s[256 + tid] * (v1 - mu) * rs + b1s[256 + tid];
            float hp_h = g1s[512 + tid] * (v2 - mu) * rs + b1s[512 + tid];
            float xr = xp_lds[tid], xz = xp_lds[256 + tid], xh = xp_lds[512 + tid];
            float r  = 1.f / (1.f + expf(-(xr + hp_r)));
            float z  = 1.f / (1.f + expf(-(xz + hp_z)));
            float hh = tanhf(xh + r * hp_h);
            float o  = z * h_pad[HIDX(tid)] + (1.f - z) * hh;
            h_pad[HIDX(tid)] = o;
            if (s == 0) Y[((long)l * BB + b) * HH + tid] = o;
        }
        __syncthreads();                               // B3: h ready
    }
}

// ---------------------------------------------------------------------------
// Fused T-GEMM + action head (T never materialized). Round-6 col mapping:
// thread's 8 cols = {tx*4..+3} u {64+tx*4..+3} (Bs read 2-way, free).
__global__ __launch_bounds__(256) void gemmact_kernel(
    const float* __restrict__ Yprev,
    const float* __restrict__ Ua1,
    const float* __restrict__ XA,
    const float* __restrict__ Wa2,
    const float* __restrict__ ba2,
    const int* __restrict__ mask_in, int* __restrict__ mask_out,
    float* __restrict__ act_out, float* __restrict__ pol_out, int d)
{
    __shared__ float As[16][132];
    __shared__ float Bs[16][132];
    const int tid = threadIdx.x;
    const int tx = tid & 15, ty = tid >> 4;
    const int row0 = blockIdx.y * 128;

    float acc[8][8];
#pragma unroll
    for (int i = 0; i < 8; ++i)
#pragma unroll
        for (int j = 0; j < 8; ++j) acc[i][j] = 0.f;

    for (int kk = 0; kk < 256; kk += 16) {
#pragma unroll
        for (int i = 0; i < 2; ++i) {
            int aid = i * 256 + tid;
            int r   = aid >> 2;
            int k4  = (aid & 3) << 2;
            int rr  = row0 + r;
            float4 v;
            if (rr < 64) v = make_float4(0.f, 0.f, 0.f, 0.f);
            else         v = *(const float4*)(Yprev + (rr - 64) * 256 + kk + k4);
            As[k4 + 0][r] = v.x; As[k4 + 1][r] = v.y;
            As[k4 + 2][r] = v.z; As[k4 + 3][r] = v.w;

            int bid = i * 256 + tid;
            int bk  = bid >> 5;
            int c4  = (bid & 31) << 2;
            float4 w = *(const float4*)(Ua1 + (kk + bk) * AA + c4);
            *(float4*)&Bs[bk][c4] = w;
        }
        __syncthreads();
#pragma unroll
        for (int k = 0; k < 16; ++k) {
            float a[8], bb2[8];
            *(float4*)&a[0]   = *(const float4*)&As[k][ty * 8];
            *(float4*)&a[4]   = *(const float4*)&As[k][ty * 8 + 4];
            *(float4*)&bb2[0] = *(const float4*)&Bs[k][tx * 4];
            *(float4*)&bb2[4] = *(const float4*)&Bs[k][64 + tx * 4];
#pragma unroll
            for (int i = 0; i < 8; ++i)
#pragma unroll
                for (int j = 0; j < 8; ++j)
                    acc[i][j] += a[i] * bb2[j];
        }
        __syncthreads();
    }

    // epilogue: tanh + per-row logit partials over this thread's 8 cols
    float p0[8], p1[8];
#pragma unroll
    for (int i = 0; i < 8; ++i) { p0[i] = 0.f; p1[i] = 0.f; }
#pragma unroll
    for (int i = 0; i < 8; ++i) {
        int row = row0 + ty * 8 + i;
#pragma unroll
        for (int j = 0; j < 8; ++j) {
            int c   = (j < 4) ? (tx * 4 + j) : (64 + tx * 4 + (j - 4));
            float v = tanhf(acc[i][j] + XA[row * AA + c]);
            p0[i] += v * Wa2[c * 2];
            p1[i] += v * Wa2[c * 2 + 1];
        }
    }
#pragma unroll
    for (int off = 1; off < 16; off <<= 1) {
#pragma unroll
        for (int i = 0; i < 8; ++i) {
            p0[i] += __shfl_xor(p0[i], off);
            p1[i] += __shfl_xor(p1[i], off);
        }
    }
    if (tx == 0) {
#pragma unroll
        for (int i = 0; i < 8; ++i) {
            int row = row0 + ty * 8 + i;
            int l   = row >> 6, bb = row & 63;
            float l0 = p0[i] + ba2[0];
            float l1 = p1[i] + ba2[1];
            float m  = fmaxf(l0, l1);
            float e0 = expf(l0 - m), e1 = expf(l1 - m);
            float inv = 1.f / (e0 + e1);
            float q0 = e0 * inv, q1v = e1 * inv;
            int mt = mask_in[bb * LL + l];
            int a  = (q1v > q0) && mt;
            act_out[bb * (NDEPTH * LL) + d * LL + l] = a ? 1.f : 0.f;
            pol_out[bb * (NDEPTH * LL * 2) + d * (LL * 2) + l * 2 + 0] = q0;
            pol_out[bb * (NDEPTH * LL * 2) + d * (LL * 2) + l * 2 + 1] = q1v;
            mask_out[bb * LL + l] = a;
        }
    }
}

// ---------------------------------------------------------------------------
__global__ void final_copy_kernel(const float* __restrict__ X, float* __restrict__ out)
{
    int i = blockIdx.x * blockDim.x + threadIdx.x;   // 16384
    int bb = i >> 8, j = i & 255;
    out[i] = X[((long)(LL - 1) * BB + bb) * HH + j];
}

// ---------------------------------------------------------------------------
extern "C" void kernel_launch(void* const* d_in, const int* in_sizes, int n_in,
                              void* d_out, int out_size, void* d_ws, size_t ws_size,
                              hipStream_t stream)
{
    const float* x      = (const float*)d_in[0];
    const void*  mraw   = d_in[1];
    const float* W_emb  = (const float*)d_in[2];
    const float* b_emb  = (const float*)d_in[3];
    const float* W      = (const float*)d_in[4];
    const float* U      = (const float*)d_in[5];
    const float* bias3  = (const float*)d_in[6];
    const float* Wa1    = (const float*)d_in[7];
    const float* Ua1    = (const float*)d_in[8];
    const float* ba1    = (const float*)d_in[9];
    const float* Wa2    = (const float*)d_in[10];
    const float* ba2    = (const float*)d_in[11];
    const float* gammas = (const float*)d_in[12];
    const float* betas  = (const float*)d_in[13];

    float* out = (float*)d_out;
    char*  ws  = (char*)d_ws;

    // workspace layout (bytes) — 185.6 MB
    float* XP = (float*)(ws);                                   // 100663296
    float* X  = (float*)(ws + 100663296UL);                     // 33554432
    float* Y  = (float*)(ws + 134217728UL);                     // 33554432
    float* XA = (float*)(ws + 167772160UL);                     // 16777216
    int*   m0 = (int*)(ws + 184549376UL);                       // 131072
    int*   m1 = (int*)(ws + 184680448UL);                       // 131072
    unsigned long long* exch_d = (unsigned long long*)(ws + 184811520UL); // 786432

    float* act_out = out + BB * HH;                             // 16384
    float* pol_out = act_out + BB * NDEPTH * LL;                // +131072

    maskcvt_kernel<<<dim3(NROWS / 256), dim3(256), 0, stream>>>(
        (const unsigned char*)mraw, m0);

    // embedding: X = x @ W_emb + b_emb, time-major rows (l*64+b)
    gemm_kernel<1, 1><<<dim3(2, 256), dim3(256), 0, stream>>>(
        x, W_emb, b_emb, X, NROWS, HH, nullptr, nullptr);

    float* Xc = X; float* Yc = Y;
    int* mc = m0; int* mn = m1;

    for (int d = 0; d < NDEPTH; ++d) {
        int* rowidx = (int*)Yc;            // 32768 ints
        int* nactp  = ((int*)Yc) + NROWS;  // 64 ints

        mkidx_kernel<<<dim3(BB), dim3(512), 0, stream>>>(mc, rowidx, nactp);

        gemm_kernel<3, 0><<<dim3(6, 256), dim3(256), 0, stream>>>(
            Xc, W, nullptr, XP, NROWS, H3, rowidx, nactp);
        lnrows_kernel<<<dim3(NROWS), dim3(256), 0, stream>>>(
            XP, gammas, betas, bias3, nactp);

        scan3_kernel<<<dim3(448), dim3(512), 0, stream>>>(
            XP, U, gammas + H3, betas + H3, mc, Yc, exch_d, d << 10,
            Xc, Wa1, ba1, XA);

        gemmact_kernel<<<dim3(1, 256), dim3(256), 0, stream>>>(
            Yc, Ua1, XA, Wa2, ba2, mc, mn, act_out, pol_out, d);

        { float* tmp = Xc; Xc = Yc; Yc = tmp; }
        { int* tmp = mc; mc = mn; mn = tmp; }
    }

    final_copy_kernel<<<dim3(BB), dim3(256), 0, stream>>>(Xc, out);
}